// Round 9
// baseline (2323.471 us; speedup 1.0000x reference)
//
#include <hip/hip_runtime.h>
#include <hip/hip_fp8.h>
#include <cstdint>
#include <cstddef>

typedef __bf16 bf16_t;
typedef unsigned char fp8_t;
typedef __attribute__((ext_vector_type(8))) __bf16 bf16x8;
typedef __attribute__((ext_vector_type(4))) float f32x4;

__device__ __forceinline__ void async_cp16(const void* g, void* l) {
    __builtin_amdgcn_global_load_lds(
        (const __attribute__((address_space(1))) void*)g,
        (__attribute__((address_space(3))) void*)l,
        16, 0, 0);
}

__device__ __forceinline__ fp8_t to_fp8(float x) {
    __hip_fp8_e4m3 t(x);
    return t.__x;
}
__device__ __forceinline__ float from_fp8(fp8_t b) {
    __hip_fp8_e4m3 t;
    t.__x = b;
    return (float)t;
}

__device__ __forceinline__ float fast_tanh(float x) {
    float ax = fabsf(x);
    float e = __expf(-2.f * ax);
    float t = (1.f - e) / (1.f + e);
    return x < 0.f ? -t : t;
}
__device__ __forceinline__ float fast_sig(float x) {
    return 1.f / (1.f + __expf(-x));
}

// ---------------- conversion kernels ----------------
__global__ void k_cvt_transpose8(const float* __restrict__ src, fp8_t* __restrict__ dst,
                                 int K, int N) {
    int idx = blockIdx.x * 256 + threadIdx.x;
    if (idx >= K * N) return;
    int k = idx / N, n = idx - k * N;
    dst[(size_t)n * K + k] = to_fp8(src[idx]);
}

__global__ void k_cvt_flat(const float* __restrict__ src, bf16_t* __restrict__ dst, int n) {
    int idx = blockIdx.x * 256 + threadIdx.x;
    if (idx >= n) return;
    dst[idx] = (bf16_t)src[idx];
}

__global__ void k_build_wrz(const float* __restrict__ Wih, const float* __restrict__ Whh,
                            const float* __restrict__ bih, const float* __restrict__ bhh,
                            bf16_t* __restrict__ wrz, float* __restrict__ brz) {
    int idx = blockIdx.x * 256 + threadIdx.x;
    if (idx >= 2048 * 1280) return;
    int n = idx / 1280, c = idx - n * 1280;
    float v = (c < 256) ? Wih[(size_t)n * 256 + c] : Whh[(size_t)n * 1024 + (c - 256)];
    wrz[idx] = (bf16_t)v;
    if (c == 0) brz[n] = bih[n] + bhh[n];
}

__global__ void k_cvt_x(const float* __restrict__ xt, bf16_t* __restrict__ xh, int B) {
    int idx = blockIdx.x * 256 + threadIdx.x;
    if (idx >= B * 256) return;
    int b = idx >> 8, c = idx & 255;
    xh[(size_t)b * 1280 + c] = (bf16_t)xt[idx];
}

// h0 dual-cast: bf16 copy (epilogue h0 reads) + fp8 copy (stage-0 tanh GEMM A)
__global__ void k_cvt_h0(const float* __restrict__ state, bf16_t* __restrict__ h0b,
                         fp8_t* __restrict__ hs8, int B) {
    int idx = blockIdx.x * 256 + threadIdx.x;
    if (idx >= B * 1024) return;
    int b = idx >> 10, j = idx & 1023;
    float v = state[(size_t)b * 1040 + 16 + j];
    h0b[idx] = (bf16_t)v;
    hs8[idx] = to_fp8(v);
}

enum { EPI_TANH = 0, EPI_RK4 = 1, EPI_SIG = 2, EPI_BIASBF = 3, EPI_FIN = 4 };

// =====================================================================
// fp8 GEMM (RK4 chain only): C = A(MxK) * Bt(NxK)^T, e4m3 in, f32 acc.
// 8-phase schedule (verified ledger), 256x256 tile, BK=64, 512 threads,
// LDS 64 KiB (2 dbuf x 2 kk x 256 x 32 fp8/operand).  vmcnt(3) gates.
// 16B-slot swizzle s16 ^= (row>>2)&1 (2-way residual = free).
// =====================================================================
template <int EPI, int STAGE>
__global__ __launch_bounds__(512, 2) void gemm256f8(
    const fp8_t* __restrict__ A, int lda,
    const fp8_t* __restrict__ Bt,
    int N, int K,
    const float* __restrict__ bias,
    fp8_t* __restrict__ o8,           // TANH: T8; RK4 0-2: hs8
    const bf16_t* __restrict__ h0b,   // RK4 0-2: h0 (bf16)
    const float* __restrict__ state,  // RK4 3: f32 ld 1040
    bf16_t* __restrict__ kacc,        // RK4: k-sum (bf16)
    float* __restrict__ outp,         // RK4 3: f32 out ld 1040
    bf16_t* __restrict__ xhb)         // RK4 3: = xh + 256 (ld 1280) bf16 ht
{
    __shared__ __align__(16) fp8_t dsA[32768];
    __shared__ __align__(16) fp8_t dsB[32768];

    const int tid  = threadIdx.x;
    const int lane = tid & 63;
    const int wv   = tid >> 6;

    const int gx  = gridDim.x;
    int bid = blockIdx.y * gx + blockIdx.x;
    const int nwg = gx * gridDim.y;
    if ((nwg & 7) == 0) bid = (bid & 7) * (nwg >> 3) + (bid >> 3);
    const int bm = (bid / gx) << 8;
    const int bn = (bid % gx) << 8;

    const int wm = (wv >> 2) << 7;
    const int wn = (wv & 3) << 6;

    f32x4 acc[8][4] = {};

    const int srow = tid >> 1;                          // 0..255
    const int s16  = tid & 1;
    const int ssw  = (s16 ^ ((srow >> 2) & 1)) << 4;
    const fp8_t* gA_s = A  + (size_t)(bm + srow) * lda + ssw;
    const fp8_t* gB_s = Bt + (size_t)(bn + srow) * K + ssw;
    const int dst0 = tid << 4;

#define STG_A(t, kkv) async_cp16(gA_s + (size_t)(t) * 64 + (kkv) * 32,          \
                                 (void*)&dsA[((t) & 1) * 16384 + (kkv) * 8192 + dst0])
#define STG_B(t, kkv) async_cp16(gB_s + (size_t)(t) * 64 + (kkv) * 32,          \
                                 (void*)&dsB[((t) & 1) * 16384 + (kkv) * 8192 + dst0])

    const int fr  = lane & 15;
    const int kg  = lane >> 4;
    const int swz = ((fr >> 2) & 1) << 1;
    const int aBase = (wm + fr) * 32 + ((kg ^ swz) << 3);
    const int bBase = (wn + fr) * 32 + ((kg ^ swz) << 3);

#define DS_A(dst, ih, kkv, bufv) do {                                           \
        const fp8_t* _p = &dsA[(bufv) * 16384 + (kkv) * 8192 + aBase + (ih) * 2048]; \
        dst[0] = *(const long*)(_p);                                            \
        dst[1] = *(const long*)(_p + 512);                                      \
        dst[2] = *(const long*)(_p + 1024);                                     \
        dst[3] = *(const long*)(_p + 1536);                                     \
    } while (0)
#define DS_B(dst, kkv, bufv) do {                                               \
        const fp8_t* _p = &dsB[(bufv) * 16384 + (kkv) * 8192 + bBase];          \
        dst[0] = *(const long*)(_p);                                            \
        dst[1] = *(const long*)(_p + 512);                                      \
        dst[2] = *(const long*)(_p + 1024);                                     \
        dst[3] = *(const long*)(_p + 1536);                                     \
    } while (0)

#define MFMA_Q(am, ib) do {                                                     \
        __builtin_amdgcn_s_setprio(1);                                          \
        _Pragma("unroll")                                                       \
        for (int x = 0; x < 4; ++x)                                             \
        _Pragma("unroll")                                                       \
        for (int j = 0; j < 4; ++j)                                             \
            acc[(ib) + x][j] = __builtin_amdgcn_mfma_f32_16x16x32_fp8_fp8(      \
                am[x], bF[j], acc[(ib) + x][j], 0, 0, 0);                       \
        __builtin_amdgcn_s_setprio(0);                                          \
    } while (0)

#define BAR()  __builtin_amdgcn_s_barrier()
#define LG0()  do { asm volatile("s_waitcnt lgkmcnt(0)" ::: "memory");          \
                    __builtin_amdgcn_sched_barrier(0); } while (0)

    const int NT = K >> 6;
    const int NI = NT >> 1;

    long aL[4], aH[4], bF[4];

    STG_B(0, 0); STG_A(0, 0); STG_B(0, 1); STG_A(0, 1);
    STG_B(1, 0); STG_A(1, 0); STG_B(1, 1); STG_A(1, 1);
    asm volatile("s_waitcnt vmcnt(4)" ::: "memory");
    BAR();

    for (int s = 0; s < NI; ++s) {
        const int t1 = 2 * s + 1;
        const int ta = 2 * s + 2;
        const int tb = 2 * s + 3;
        const bool more = (s + 1 < NI);

        DS_A(aL, 0, 0, 0); DS_B(bF, 0, 0);
        if (s > 0) STG_A(t1, 1);
        BAR(); LG0(); MFMA_Q(aL, 0); BAR();

        DS_A(aH, 1, 0, 0);
        if (more) STG_B(ta, 0);
        BAR(); LG0(); MFMA_Q(aH, 4); BAR();

        DS_A(aL, 0, 1, 0); DS_B(bF, 1, 0);
        if (more) STG_A(ta, 0);
        BAR(); LG0(); MFMA_Q(aL, 0); BAR();

        DS_A(aH, 1, 1, 0);
        if (more) STG_B(ta, 1);
        BAR(); LG0(); MFMA_Q(aH, 4);
        if (more) asm volatile("s_waitcnt vmcnt(3)" ::: "memory");
        else      asm volatile("s_waitcnt vmcnt(0)" ::: "memory");
        BAR();

        DS_A(aL, 0, 0, 1); DS_B(bF, 0, 1);
        if (more) STG_A(ta, 1);
        BAR(); LG0(); MFMA_Q(aL, 0); BAR();

        DS_A(aH, 1, 0, 1);
        if (more) STG_B(tb, 0);
        BAR(); LG0(); MFMA_Q(aH, 4); BAR();

        DS_A(aL, 0, 1, 1); DS_B(bF, 1, 1);
        if (more) STG_A(tb, 0);
        BAR(); LG0(); MFMA_Q(aL, 0); BAR();

        DS_A(aH, 1, 1, 1);
        if (more) STG_B(tb, 1);
        BAR(); LG0(); MFMA_Q(aH, 4);
        if (more) asm volatile("s_waitcnt vmcnt(3)" ::: "memory");
        else      asm volatile("s_waitcnt vmcnt(0)" ::: "memory");
        BAR();
    }
#undef STG_A
#undef STG_B
#undef DS_A
#undef DS_B
#undef MFMA_Q
#undef BAR
#undef LG0

    const int orow0 = bm + wm + (kg << 2);
    const int ocol0 = bn + wn + fr;
#pragma unroll
    for (int i = 0; i < 8; ++i) {
#pragma unroll
        for (int j = 0; j < 4; ++j) {
#pragma unroll
            for (int r = 0; r < 4; ++r) {
                const int row = orow0 + i * 16 + r;
                const int col = ocol0 + j * 16;
                const float c = acc[i][j][r];
                if constexpr (EPI == EPI_TANH) {
                    o8[(size_t)row * N + col] = to_fp8(fast_tanh(c + bias[col]));
                } else {  // EPI_RK4
                    const float kk = c + bias[col];
                    const size_t hidx = ((size_t)row << 10) + col;
                    if constexpr (STAGE == 0) {
                        const float h0 = (float)h0b[hidx];
                        kacc[hidx] = (bf16_t)kk;
                        o8[hidx] = to_fp8(h0 + 0.05f * kk);
                    } else if constexpr (STAGE == 1) {
                        const float h0 = (float)h0b[hidx];
                        kacc[hidx] = (bf16_t)((float)kacc[hidx] + 2.f * kk);
                        o8[hidx] = to_fp8(h0 + 0.05f * kk);
                    } else if constexpr (STAGE == 2) {
                        const float h0 = (float)h0b[hidx];
                        kacc[hidx] = (bf16_t)((float)kacc[hidx] + 2.f * kk);
                        o8[hidx] = to_fp8(h0 + 0.1f * kk);
                    } else {
                        const float h0 = state[(size_t)row * 1040 + 16 + col];
                        const float ht = h0 + (0.1f / 6.f) * ((float)kacc[hidx] + kk);
                        outp[(size_t)row * 1040 + 16 + col] = ht;
                        xhb[(size_t)row * 1280 + col] = (bf16_t)ht;
                    }
                }
            }
        }
    }
}

// =====================================================================
// bf16 GEMM (GRU): 8-phase, 256x256, BK=64, 512 threads, LDS 128 KiB.
// vmcnt(6) gates.  Slot-XOR swizzle s4 ^= (row>>1)&3 (0 conflicts).
// =====================================================================
template <int EPI>
__global__ __launch_bounds__(512, 2) void gemm256bf(
    const bf16_t* __restrict__ A, int lda,
    const bf16_t* __restrict__ Bt,
    int N, int K,
    const float* __restrict__ bias,
    bf16_t* __restrict__ o16,         // SIG: rz; BIASBF: inb
    const bf16_t* __restrict__ rz,    // FIN
    const bf16_t* __restrict__ inb,   // FIN
    float* __restrict__ outp)         // FIN: f32 rmw ld 1040
{
    __shared__ __align__(16) bf16_t dsA[32768];
    __shared__ __align__(16) bf16_t dsB[32768];

    const int tid  = threadIdx.x;
    const int lane = tid & 63;
    const int wv   = tid >> 6;

    const int gx  = gridDim.x;
    int bid = blockIdx.y * gx + blockIdx.x;
    const int nwg = gx * gridDim.y;
    if ((nwg & 7) == 0) bid = (bid & 7) * (nwg >> 3) + (bid >> 3);
    const int bm = (bid / gx) << 8;
    const int bn = (bid % gx) << 8;

    const int wm = (wv >> 2) << 7;
    const int wn = (wv & 3) << 6;

    f32x4 acc[8][4] = {};

    const int srow  = tid >> 2;                        // 0..127
    const int sslot = tid & 3;
    const int ssw   = (sslot ^ ((srow >> 1) & 3)) << 3;
    const bf16_t* gA_s = A  + (size_t)(bm + srow) * lda + ssw;
    const bf16_t* gB_s = Bt + (size_t)(bn + srow) * K + ssw;
    const size_t a128 = (size_t)128 * lda;
    const size_t b128 = (size_t)128 * K;
    const int dst0 = srow * 32 + sslot * 8;

#define STG_A(t, kkv) do {                                                     \
        const int _pl = ((t) & 1) * 16384 + (kkv) * 8192;                      \
        const size_t _go = (size_t)(t) * 64 + (kkv) * 32;                      \
        async_cp16(gA_s + _go,        (void*)&dsA[_pl + dst0]);                \
        async_cp16(gA_s + a128 + _go, (void*)&dsA[_pl + dst0 + 4096]);         \
    } while (0)
#define STG_B(t, kkv) do {                                                     \
        const int _pl = ((t) & 1) * 16384 + (kkv) * 8192;                      \
        const size_t _go = (size_t)(t) * 64 + (kkv) * 32;                      \
        async_cp16(gB_s + _go,        (void*)&dsB[_pl + dst0]);                \
        async_cp16(gB_s + b128 + _go, (void*)&dsB[_pl + dst0 + 4096]);         \
    } while (0)

    const int fr   = lane & 15;
    const int kg   = lane >> 4;
    const int frsw = (fr >> 1) & 3;
    const int aBase = (wm + fr) * 32 + ((kg ^ frsw) << 3);
    const int bBase = (wn + fr) * 32 + ((kg ^ frsw) << 3);

#define DS_A(dst, ih, kkv, bufv) do {                                          \
        const bf16_t* _p = &dsA[(bufv) * 16384 + (kkv) * 8192 + aBase + (ih) * 2048]; \
        dst[0] = *(const bf16x8*)(_p);                                         \
        dst[1] = *(const bf16x8*)(_p + 512);                                   \
        dst[2] = *(const bf16x8*)(_p + 1024);                                  \
        dst[3] = *(const bf16x8*)(_p + 1536);                                  \
    } while (0)
#define DS_B(dst, kkv, bufv) do {                                              \
        const bf16_t* _p = &dsB[(bufv) * 16384 + (kkv) * 8192 + bBase];        \
        dst[0] = *(const bf16x8*)(_p);                                         \
        dst[1] = *(const bf16x8*)(_p + 512);                                   \
        dst[2] = *(const bf16x8*)(_p + 1024);                                  \
        dst[3] = *(const bf16x8*)(_p + 1536);                                  \
    } while (0)

#define MFMA_Q(am, ib) do {                                                    \
        __builtin_amdgcn_s_setprio(1);                                         \
        _Pragma("unroll")                                                      \
        for (int x = 0; x < 4; ++x)                                            \
        _Pragma("unroll")                                                      \
        for (int j = 0; j < 4; ++j)                                            \
            acc[(ib) + x][j] = __builtin_amdgcn_mfma_f32_16x16x32_bf16(        \
                am[x], bF[j], acc[(ib) + x][j], 0, 0, 0);                      \
        __builtin_amdgcn_s_setprio(0);                                         \
    } while (0)

#define BAR()  __builtin_amdgcn_s_barrier()
#define LG0()  do { asm volatile("s_waitcnt lgkmcnt(0)" ::: "memory");         \
                    __builtin_amdgcn_sched_barrier(0); } while (0)

    const int NT = K >> 6;
    const int NI = NT >> 1;

    bf16x8 aL[4], aH[4], bF[4];

    STG_A(0, 0); STG_B(0, 0); STG_A(0, 1); STG_B(0, 1);
    STG_A(1, 0); STG_B(1, 0); STG_A(1, 1); STG_B(1, 1);
    asm volatile("s_waitcnt vmcnt(8)" ::: "memory");
    BAR();

    for (int s = 0; s < NI; ++s) {
        const int t1 = 2 * s + 1;
        const int ta = 2 * s + 2;
        const int tb = 2 * s + 3;
        const bool more = (s + 1 < NI);

        DS_A(aL, 0, 0, 0); DS_B(bF, 0, 0);
        if (s > 0) STG_A(t1, 1);
        BAR(); LG0(); MFMA_Q(aL, 0); BAR();

        DS_A(aH, 1, 0, 0);
        if (more) STG_B(ta, 0);
        BAR(); LG0(); MFMA_Q(aH, 4); BAR();

        DS_A(aL, 0, 1, 0); DS_B(bF, 1, 0);
        if (more) STG_A(ta, 0);
        BAR(); LG0(); MFMA_Q(aL, 0); BAR();

        DS_A(aH, 1, 1, 0);
        if (more) STG_B(ta, 1);
        BAR(); LG0(); MFMA_Q(aH, 4);
        if (more) asm volatile("s_waitcnt vmcnt(6)" ::: "memory");
        else      asm volatile("s_waitcnt vmcnt(0)" ::: "memory");
        BAR();

        DS_A(aL, 0, 0, 1); DS_B(bF, 0, 1);
        if (more) STG_A(ta, 1);
        BAR(); LG0(); MFMA_Q(aL, 0); BAR();

        DS_A(aH, 1, 0, 1);
        if (more) STG_B(tb, 0);
        BAR(); LG0(); MFMA_Q(aH, 4); BAR();

        DS_A(aL, 0, 1, 1); DS_B(bF, 1, 1);
        if (more) STG_A(tb, 0);
        BAR(); LG0(); MFMA_Q(aL, 0); BAR();

        DS_A(aH, 1, 1, 1);
        if (more) STG_B(tb, 1);
        BAR(); LG0(); MFMA_Q(aH, 4);
        if (more) asm volatile("s_waitcnt vmcnt(6)" ::: "memory");
        else      asm volatile("s_waitcnt vmcnt(0)" ::: "memory");
        BAR();
    }
#undef STG_A
#undef STG_B
#undef DS_A
#undef DS_B
#undef MFMA_Q
#undef BAR
#undef LG0

    const int orow0 = bm + wm + (kg << 2);
    const int ocol0 = bn + wn + fr;
#pragma unroll
    for (int i = 0; i < 8; ++i) {
#pragma unroll
        for (int j = 0; j < 4; ++j) {
#pragma unroll
            for (int r = 0; r < 4; ++r) {
                const int row = orow0 + i * 16 + r;
                const int col = ocol0 + j * 16;
                const float c = acc[i][j][r];
                if constexpr (EPI == EPI_SIG) {
                    o16[(size_t)row * N + col] = (bf16_t)fast_sig(c + bias[col]);
                } else if constexpr (EPI == EPI_BIASBF) {
                    o16[(size_t)row * N + col] = (bf16_t)(c + bias[col]);
                } else {  // EPI_FIN
                    const float hn  = c + bias[col];
                    const float r_  = (float)rz[((size_t)row << 11) + col];
                    const float z_  = (float)rz[((size_t)row << 11) + 1024 + col];
                    const float inv = (float)inb[((size_t)row << 10) + col];
                    const float nn  = fast_tanh(inv + r_ * hn);
                    const size_t oidx = (size_t)row * 1040 + 16 + col;
                    const float htv = outp[oidx];        // exact f32 ht (stage 3)
                    outp[oidx] = (1.f - z_) * nn + z_ * htv;
                }
            }
        }
    }
}

// ---------------- readout: out[:, :16] ----------------
__global__ void k_ly(const float* __restrict__ outh, const float* __restrict__ state,
                     const float* __restrict__ Wly, const float* __restrict__ bly,
                     const int* __restrict__ y_type, float* __restrict__ outp, int B) {
    int t = blockIdx.x * 256 + threadIdx.x;
    if (t >= B * 16) return;
    int o = t & 15, b = t >> 4;
    const float4* hrow = (const float4*)(outh + (size_t)b * 1040 + 16);
    float s = bly[o];
#pragma unroll 4
    for (int k4 = 0; k4 < 256; ++k4) {
        float4 h = hrow[k4];
        int k = k4 << 2;
        s += h.x * Wly[(k + 0) * 16 + o] + h.y * Wly[(k + 1) * 16 + o]
           + h.z * Wly[(k + 2) * 16 + o] + h.w * Wly[(k + 3) * 16 + o];
    }
    outp[(size_t)b * 1040 + o] = (y_type[o] == 0) ? s : state[(size_t)b * 1040 + o];
}

// ---------------- launcher ----------------
extern "C" void kernel_launch(void* const* d_in, const int* in_sizes, int n_in,
                              void* d_out, int out_size, void* d_ws, size_t ws_size,
                              hipStream_t stream) {
    const float* state = (const float*)d_in[0];
    const float* xt    = (const float*)d_in[1];
    const float* W1    = (const float*)d_in[2];
    const float* b1    = (const float*)d_in[3];
    const float* W2    = (const float*)d_in[4];
    const float* b2    = (const float*)d_in[5];
    const float* Wih   = (const float*)d_in[6];
    const float* Whh   = (const float*)d_in[7];
    const float* bih   = (const float*)d_in[8];
    const float* bhh   = (const float*)d_in[9];
    const float* Wly   = (const float*)d_in[10];
    const float* bly   = (const float*)d_in[11];
    const int*   y_type = (const int*)d_in[12];
    float* out = (float*)d_out;

    const int B = in_sizes[0] / 1040;   // 32768

    char* ws = (char*)d_ws;
    fp8_t*  w1t8 = (fp8_t*) (ws);                    // 2048 x 1024 fp8   (2 MB)
    fp8_t*  w2t8 = (fp8_t*) (ws + 2097152);          // 1024 x 2048 fp8   (2 MB)
    bf16_t* wrz  = (bf16_t*)(ws + 4194304);          // 2048 x 1280 bf16  (5 MB)
    bf16_t* win  = (bf16_t*)(ws + 9437184);          // 1024 x 256 bf16
    bf16_t* whn  = (bf16_t*)(ws + 9961472);          // 1024 x 1024 bf16  (2 MB)
    float*  brz  = (float*) (ws + 12058624);         // 2048
    bf16_t* xh   = (bf16_t*)(ws + 12066816);         // B x 1280 bf16 [x|ht] (80 MB)
    fp8_t*  hs8  = (fp8_t*) (ws + 95952896);         // B x 1024 fp8 stage-h (32 MB)
    bf16_t* kacc = (bf16_t*)(ws + 129507328);        // B x 1024 bf16 k-sum  (64 MB)
    fp8_t*  T8   = (fp8_t*) (ws + 196616192);        // B x 2048 fp8 tanh    (64 MB)
    bf16_t* h0b  = (bf16_t*)(ws + 263725056);        // B x 1024 bf16 h0     (64 MB)
    // overlays (after RK4 completes):
    bf16_t* rz   = (bf16_t*)(ws + 196616192);        // B x 2048 bf16 (over T8+h0b)
    bf16_t* inb  = (bf16_t*)(ws + 95952896);         // B x 1024 bf16 (over hs8+kacc)

    // weight prep + input casts
    k_cvt_transpose8<<<(1024 * 2048) / 256, 256, 0, stream>>>(W1, w1t8, 1024, 2048);
    k_cvt_transpose8<<<(2048 * 1024) / 256, 256, 0, stream>>>(W2, w2t8, 2048, 1024);
    k_build_wrz<<<(2048 * 1280) / 256, 256, 0, stream>>>(Wih, Whh, bih, bhh, wrz, brz);
    k_cvt_flat<<<(1024 * 256) / 256, 256, 0, stream>>>(Wih + 2048 * 256, win, 1024 * 256);
    k_cvt_flat<<<(1024 * 1024) / 256, 256, 0, stream>>>(Whh + 2048 * 1024, whn, 1024 * 1024);
    k_cvt_x<<<(B * 256) / 256, 256, 0, stream>>>(xt, xh, B);
    k_cvt_h0<<<(B * 1024) / 256, 256, 0, stream>>>(state, h0b, hs8, B);

    const dim3 blk(512);
    const int MB = B / 256;   // 128 m-tiles

    // ---- RK4 (fp8 GEMMs, dt/6-damped error path) ----
    gemm256f8<EPI_TANH, 0><<<dim3(8, MB), blk, 0, stream>>>(hs8, 1024, w1t8, 2048, 1024,
        b1, T8, nullptr, nullptr, nullptr, nullptr, nullptr);
    gemm256f8<EPI_RK4, 0><<<dim3(4, MB), blk, 0, stream>>>(T8, 2048, w2t8, 1024, 2048,
        b2, hs8, h0b, state, kacc, out, xh + 256);

    gemm256f8<EPI_TANH, 0><<<dim3(8, MB), blk, 0, stream>>>(hs8, 1024, w1t8, 2048, 1024,
        b1, T8, nullptr, nullptr, nullptr, nullptr, nullptr);
    gemm256f8<EPI_RK4, 1><<<dim3(4, MB), blk, 0, stream>>>(T8, 2048, w2t8, 1024, 2048,
        b2, hs8, h0b, state, kacc, out, xh + 256);

    gemm256f8<EPI_TANH, 0><<<dim3(8, MB), blk, 0, stream>>>(hs8, 1024, w1t8, 2048, 1024,
        b1, T8, nullptr, nullptr, nullptr, nullptr, nullptr);
    gemm256f8<EPI_RK4, 2><<<dim3(4, MB), blk, 0, stream>>>(T8, 2048, w2t8, 1024, 2048,
        b2, hs8, h0b, state, kacc, out, xh + 256);

    gemm256f8<EPI_TANH, 0><<<dim3(8, MB), blk, 0, stream>>>(hs8, 1024, w1t8, 2048, 1024,
        b1, T8, nullptr, nullptr, nullptr, nullptr, nullptr);
    gemm256f8<EPI_RK4, 3><<<dim3(4, MB), blk, 0, stream>>>(T8, 2048, w2t8, 1024, 2048,
        b2, hs8, h0b, state, kacc, out, xh + 256);

    // ---- GRU (bf16 GEMMs) ----
    gemm256bf<EPI_SIG><<<dim3(8, MB), blk, 0, stream>>>(xh, 1280, wrz, 2048, 1280,
        brz, rz, nullptr, nullptr, nullptr);
    gemm256bf<EPI_BIASBF><<<dim3(4, MB), blk, 0, stream>>>(xh, 1280, win, 1024, 256,
        bih + 2048, inb, nullptr, nullptr, nullptr);
    gemm256bf<EPI_FIN><<<dim3(4, MB), blk, 0, stream>>>(xh + 256, 1280, whn, 1024, 1024,
        bhh + 2048, nullptr, rz, inb, out);

    // ---- readout out[:, :16] ----
    k_ly<<<(B * 16) / 256, 256, 0, stream>>>(out, state, Wly, bly, y_type, out, B);
}